// Round 2
// baseline (1060.816 us; speedup 1.0000x reference)
//
#include <hip/hip_runtime.h>

#define SQ 1024
#define DM 1024
#define NH 16
#define HD 64
#define NL 6
#define DFF 4096
#define EPS 1.1920929e-07f

typedef __attribute__((ext_vector_type(8))) short short8;
typedef __attribute__((ext_vector_type(4))) float floatx4;
typedef __attribute__((address_space(1))) const unsigned int GU32;
typedef __attribute__((address_space(3))) unsigned int LU32;

__device__ __forceinline__ unsigned short f2b(float f) {
    union { float f; unsigned int u; } x; x.f = f;
    unsigned int r = x.u + 0x7fffu + ((x.u >> 16) & 1u);
    return (unsigned short)(r >> 16);
}

__device__ __forceinline__ float wsum(float v) {
#pragma unroll
    for (int m = 32; m >= 1; m >>= 1) v += __shfl_xor(v, m, 64);
    return v;
}
__device__ __forceinline__ float bsum(float v) {
    __shared__ float sh[4];
    v = wsum(v);
    __syncthreads();
    if ((threadIdx.x & 63) == 0) sh[threadIdx.x >> 6] = v;
    __syncthreads();
    return sh[0] + sh[1] + sh[2] + sh[3];
}

// ---- f32 -> bf16 conversion: 32B/lane loads, 16B/lane stores ----
// per block: 4096 floats (512 float8, 2 per thread).
// small tensors: 6291456 floats = 1536 blocks each; big: 25165824 = 6144 blocks.
// grid = 4*1536 + 2*6144 = 18432.
__global__ void convert_all(const float* __restrict__ s0, const float* __restrict__ s1,
                            const float* __restrict__ s2, const float* __restrict__ s3,
                            const float* __restrict__ s4, const float* __restrict__ s5,
                            unsigned short* __restrict__ d0, unsigned short* __restrict__ d1,
                            unsigned short* __restrict__ d2, unsigned short* __restrict__ d3,
                            unsigned short* __restrict__ d4, unsigned short* __restrict__ d5) {
    int bid = blockIdx.x;
    const float* src; unsigned short* dst; long base;   // base in float8 units
    if (bid < 1536)        { src = s0; dst = d0; base = (long)bid * 512; }
    else if (bid < 3072)   { src = s1; dst = d1; base = (long)(bid - 1536) * 512; }
    else if (bid < 4608)   { src = s2; dst = d2; base = (long)(bid - 3072) * 512; }
    else if (bid < 6144)   { src = s3; dst = d3; base = (long)(bid - 4608) * 512; }
    else if (bid < 12288)  { src = s4; dst = d4; base = (long)(bid - 6144) * 512; }
    else                   { src = s5; dst = d5; base = (long)(bid - 12288) * 512; }
    long i0 = base + threadIdx.x;
#pragma unroll
    for (int u = 0; u < 2; ++u) {
        long i = i0 + u * 256;
        float4 a = ((const float4*)src)[2 * i];
        float4 b = ((const float4*)src)[2 * i + 1];
        short8 o;
        o[0] = (short)f2b(a.x); o[1] = (short)f2b(a.y);
        o[2] = (short)f2b(a.z); o[3] = (short)f2b(a.w);
        o[4] = (short)f2b(b.x); o[5] = (short)f2b(b.y);
        o[6] = (short)f2b(b.z); o[7] = (short)f2b(b.w);
        *(short8*)(dst + i * 8) = o;
    }
}

// ---- rope cos/sin table: tab[s*32+d] = (cos, sin) of s * 10000^(-2d/64) ----
__global__ void build_rope(float2* __restrict__ tab) {
    int i = blockIdx.x * 256 + threadIdx.x;     // 32768 entries
    int s = i >> 5, d = i & 31;
    float invf = expf(-((float)(2 * d) / (float)HD) * 9.210340371976184f);
    float fr = (float)s * invf;
    tab[i] = make_float2(cosf(fr), sinf(fr));
}

// ---- markov mask prep ----
__global__ void scan_levels(const int* __restrict__ levels, int* __restrict__ cpad) {
    __shared__ int sh[SQ];
    int t = threadIdx.x;
    sh[t] = (levels[t] == 0) ? 1 : 0;
    __syncthreads();
    for (int off = 1; off < SQ; off <<= 1) {
        int v = (t >= off) ? sh[t - off] : 0;
        __syncthreads();
        sh[t] += v;
        __syncthreads();
    }
    cpad[t + 1] = sh[t];
    if (t == 0) cpad[0] = 0;
}

__global__ void build_mask_bits(const int* __restrict__ levels, const int* __restrict__ sidx,
                                const int* __restrict__ cpad, unsigned long long* __restrict__ mb) {
    int i = blockIdx.x * 256 + threadIdx.x;
    int q = i >> 10, k = i & 1023;
    bool causal = q >= k;
    bool same = sidx[q] == sidx[k];
    int cnt = cpad[q] - cpad[k + 1];
    bool markov = (levels[k] == 0) && (cnt > 0);
    bool pred = causal && same && !markov;
    unsigned long long bal = __ballot(pred);
    if ((threadIdx.x & 63) == 0) mb[(size_t)q * 16 + (k >> 6)] = bal;
}

// ---- initial: r = rms(x_in); x0 = r; xl = (l0+l1)*r; xnb = bf16(rms(xl)) ----
__global__ void rms0(const float* __restrict__ xin, const float* __restrict__ lam2,
                     float* __restrict__ x0, float* __restrict__ xl,
                     unsigned short* __restrict__ xnb) {
    int row = blockIdx.x, t = threadIdx.x;
    float l0 = lam2[0], l1 = lam2[1];
    const float* rp = xin + (size_t)row * DM;
    float v[4]; float ss = 0.f;
#pragma unroll
    for (int j = 0; j < 4; ++j) { v[j] = rp[t + j * 256]; ss += v[j] * v[j]; }
    ss = bsum(ss);
    float inv = rsqrtf(ss / (float)DM + EPS);
    float coef = l0 + l1;
    float w[4]; float ss2 = 0.f;
#pragma unroll
    for (int j = 0; j < 4; ++j) {
        float r = v[j] * inv;
        x0[(size_t)row * DM + t + j * 256] = r;
        w[j] = coef * r;
        ss2 += w[j] * w[j];
    }
    ss2 = bsum(ss2);
    float inv2 = rsqrtf(ss2 / (float)DM + EPS);
#pragma unroll
    for (int j = 0; j < 4; ++j) {
        size_t idx = (size_t)row * DM + t + j * 256;
        xl[idx] = w[j];
        xnb[idx] = f2b(w[j] * inv2);
    }
}

// ---- fused QKV GEMM 64x128, double-buffered LDS ----
// z=0/1 -> head-rms + rope -> qb/kb (bf16); z=2 -> v blend + transpose -> vt (bf16)
__global__ __launch_bounds__(256, 2)
void gemm_qkv(const unsigned short* __restrict__ A,      // xn_b [S][D]
              const unsigned short* __restrict__ B0,     // wq_b + i*D*D (wk,wv at z*sB)
              long long sB,
              unsigned short* __restrict__ qb, unsigned short* __restrict__ kb,
              float* __restrict__ v1, unsigned short* __restrict__ vt,
              const float2* __restrict__ rope,
              const float* __restrict__ lambp, int first) {
    constexpr int BM = 64, BN = 128, BK = 32;
    __shared__ unsigned short As[2][BM * BK];    // 2 x 4 KB
    __shared__ unsigned short Bs[2][BN * BK];    // 2 x 8 KB
    __shared__ unsigned short vtile[128 * 72];   // 18 KB (pad 72 to break conflicts)
    int t = threadIdx.x, wave = t >> 6, lane = t & 63;
    int m0 = blockIdx.y * BM, n0 = blockIdx.x * BN;
    int z = blockIdx.z;
    const unsigned short* Bb = B0 + (size_t)z * sB;
    int r = lane & 15, q4 = lane >> 4;
    int sr = lane >> 2, sseg = lane & 3;
    int wmo = (wave >> 1) * 32, wno = (wave & 1) * 64;

    floatx4 acc[2][4] = {};

    // prologue stage (k0 = 0)
    {
        const unsigned short* g = A + (size_t)(m0 + wave * 16 + sr) * DM + sseg * 8;
        __builtin_amdgcn_global_load_lds((GU32*)g, (LU32*)(&As[0][wave * 512]), 16, 0, 0);
    }
#pragma unroll
    for (int j = 0; j < 2; ++j) {
        int c = wave * 2 + j;
        const unsigned short* g = Bb + (size_t)(n0 + c * 16 + sr) * DM + sseg * 8;
        __builtin_amdgcn_global_load_lds((GU32*)g, (LU32*)(&Bs[0][c * 512]), 16, 0, 0);
    }
    __syncthreads();

    int cur = 0;
    for (int k0 = 0; k0 < DM; k0 += BK) {
        int kn = k0 + BK;
        if (kn < DM) {
            {
                const unsigned short* g = A + (size_t)(m0 + wave * 16 + sr) * DM + kn + sseg * 8;
                __builtin_amdgcn_global_load_lds((GU32*)g, (LU32*)(&As[cur ^ 1][wave * 512]), 16, 0, 0);
            }
#pragma unroll
            for (int j = 0; j < 2; ++j) {
                int c = wave * 2 + j;
                const unsigned short* g = Bb + (size_t)(n0 + c * 16 + sr) * DM + kn + sseg * 8;
                __builtin_amdgcn_global_load_lds((GU32*)g, (LU32*)(&Bs[cur ^ 1][c * 512]), 16, 0, 0);
            }
        }
        short8 af[2], bfr[4];
#pragma unroll
        for (int mi = 0; mi < 2; ++mi)
            af[mi] = *(const short8*)(&As[cur][(wmo + mi * 16 + r) * BK + q4 * 8]);
#pragma unroll
        for (int ni = 0; ni < 4; ++ni)
            bfr[ni] = *(const short8*)(&Bs[cur][(wno + ni * 16 + r) * BK + q4 * 8]);
#pragma unroll
        for (int mi = 0; mi < 2; ++mi)
#pragma unroll
            for (int ni = 0; ni < 4; ++ni)
                acc[mi][ni] = __builtin_amdgcn_mfma_f32_16x16x32_bf16(af[mi], bfr[ni], acc[mi][ni], 0, 0, 0);
        __syncthreads();
        cur ^= 1;
    }

    if (z == 2) {
        // v blend (with v1) -> bf16 -> LDS tile -> transposed write to vt
        float l = lambp[0];
#pragma unroll
        for (int mi = 0; mi < 2; ++mi)
#pragma unroll
            for (int ni = 0; ni < 4; ++ni)
#pragma unroll
                for (int j = 0; j < 4; ++j) {
                    int row = m0 + wmo + mi * 16 + q4 * 4 + j;
                    int col = n0 + wno + ni * 16 + r;
                    float val = acc[mi][ni][j];
                    size_t gi = (size_t)row * DM + col;
                    float v1v;
                    if (first) { v1[gi] = val; v1v = val; } else v1v = v1[gi];
                    vtile[(col - n0) * 72 + (row - m0)] = f2b((1.f - l) * val + l * v1v);
                }
        __syncthreads();
#pragma unroll
        for (int jj = 0; jj < 4; ++jj) {
            int idx = jj * 256 + t;      // 0..1023
            int cr = idx >> 3;           // 0..127
            int seg = idx & 7;
            short8 o = *(const short8*)(&vtile[cr * 72 + seg * 8]);
            *(short8*)(vt + (size_t)(n0 + cr) * SQ + m0 + seg * 8) = o;
        }
        return;
    }

    unsigned short* dst = z ? kb : qb;
    // wave owns exactly one 64-col head: cols n0+wno + ni*16 + r
#pragma unroll
    for (int mi = 0; mi < 2; ++mi) {
#pragma unroll
        for (int j = 0; j < 4; ++j) {
            int row = m0 + wmo + mi * 16 + q4 * 4 + j;
            float v0 = acc[mi][0][j], v1x = acc[mi][1][j], v2 = acc[mi][2][j], v3 = acc[mi][3][j];
            float ss = v0 * v0 + v1x * v1x + v2 * v2 + v3 * v3;
#pragma unroll
            for (int d = 1; d < 16; d <<= 1) ss += __shfl_xor(ss, d, 64);
            float inv = rsqrtf(ss * (1.f / 64.f) + EPS);
            v0 *= inv; v1x *= inv; v2 *= inv; v3 *= inv;
            float2 t0 = rope[row * 32 + r];
            float2 t1 = rope[row * 32 + 16 + r];
            size_t rb = (size_t)row * DM + n0 + wno + r;
            dst[rb]      = f2b(v0 * t0.x + v2 * t0.y);
            dst[rb + 16] = f2b(v1x * t1.x + v3 * t1.y);
            dst[rb + 32] = f2b(v2 * t0.x - v0 * t0.y);
            dst[rb + 48] = f2b(v3 * t1.x - v1x * t1.y);
        }
    }
}

// ---- fused flash attention: one wave per (16-row q-tile, head) ----
__global__ __launch_bounds__(64)
void flash_attn(const unsigned short* __restrict__ qb, const unsigned short* __restrict__ kb,
                const unsigned short* __restrict__ vt, const unsigned long long* __restrict__ mb,
                unsigned short* __restrict__ yb) {
    __shared__ unsigned short Ps[16 * 64];
    int lane = threadIdx.x;
    int qt = blockIdx.x & 63, h = blockIdx.x >> 6;
    int q0 = qt * 16;
    int r = lane & 15, q4 = lane >> 4;
    const unsigned short* qp = qb + (size_t)(q0 + r) * DM + h * HD + q4 * 8;
    short8 aq0 = *(const short8*)qp;
    short8 aq1 = *(const short8*)(qp + 32);
    floatx4 o[4] = {};
    float m[4] = {-1e30f, -1e30f, -1e30f, -1e30f};
    float l[4] = {0.f, 0.f, 0.f, 0.f};
    int nk = (qt >> 2) + 1;
    for (int kt = 0; kt < nk; ++kt) {
        int k0 = kt * 64;
        unsigned long long mw[4];
#pragma unroll
        for (int j = 0; j < 4; ++j) mw[j] = mb[(size_t)(q0 + q4 * 4 + j) * 16 + kt];
        unsigned long long any = mw[0] | mw[1] | mw[2] | mw[3];
        if (__ballot(any != 0ull) == 0ull) continue;
        short8 bk[4][2], bv[4][2];
#pragma unroll
        for (int ni = 0; ni < 4; ++ni) {
            const unsigned short* kp = kb + (size_t)(k0 + ni * 16 + r) * DM + h * HD + q4 * 8;
            bk[ni][0] = *(const short8*)kp;
            bk[ni][1] = *(const short8*)(kp + 32);
            const unsigned short* vp = vt + (size_t)(h * HD + ni * 16 + r) * SQ + k0 + q4 * 8;
            bv[ni][0] = *(const short8*)vp;
            bv[ni][1] = *(const short8*)(vp + 32);
        }
        float sm[4][4];
#pragma unroll
        for (int ni = 0; ni < 4; ++ni) {
            floatx4 z = {};
            z = __builtin_amdgcn_mfma_f32_16x16x32_bf16(aq0, bk[ni][0], z, 0, 0, 0);
            z = __builtin_amdgcn_mfma_f32_16x16x32_bf16(aq1, bk[ni][1], z, 0, 0, 0);
#pragma unroll
            for (int j = 0; j < 4; ++j) {
                float sv = z[j] * 0.125f;
                bool bit = (mw[j] >> (ni * 16 + r)) & 1ull;
                sm[ni][j] = bit ? sv : -__builtin_inff();
            }
        }
        float alpha[4];
#pragma unroll
        for (int j = 0; j < 4; ++j) {
            float v = fmaxf(fmaxf(sm[0][j], sm[1][j]), fmaxf(sm[2][j], sm[3][j]));
#pragma unroll
            for (int d = 1; d < 16; d <<= 1) v = fmaxf(v, __shfl_xor(v, d, 64));
            float mn = fmaxf(m[j], v);
            alpha[j] = __expf(m[j] - mn);
            m[j] = mn;
        }
        float p[4][4];
        float rs[4] = {0.f, 0.f, 0.f, 0.f};
#pragma unroll
        for (int ni = 0; ni < 4; ++ni)
#pragma unroll
            for (int j = 0; j < 4; ++j) {
                p[ni][j] = __expf(sm[ni][j] - m[j]);
                rs[j] += p[ni][j];
            }
#pragma unroll
        for (int j = 0; j < 4; ++j) {
            float v = rs[j];
#pragma unroll
            for (int d = 1; d < 16; d <<= 1) v += __shfl_xor(v, d, 64);
            l[j] = l[j] * alpha[j] + v;
        }
#pragma unroll
        for (int ni = 0; ni < 4; ++ni)
#pragma unroll
            for (int j = 0; j < 4; ++j) {
                o[ni][j] *= alpha[j];
                Ps[(q4 * 4 + j) * 64 + ni * 16 + r] = f2b(p[ni][j]);
            }
        short8 ap0 = *(const short8*)(Ps + r * 64 + q4 * 8);
        short8 ap1 = *(const short8*)(Ps + r * 64 + 32 + q4 * 8);
#pragma unroll
        for (int ni = 0; ni < 4; ++ni) {
            o[ni] = __builtin_amdgcn_mfma_f32_16x16x32_bf16(ap0, bv[ni][0], o[ni], 0, 0, 0);
            o[ni] = __builtin_amdgcn_mfma_f32_16x16x32_bf16(ap1, bv[ni][1], o[ni], 0, 0, 0);
        }
    }
#pragma unroll
    for (int j = 0; j < 4; ++j) l[j] = 1.f / l[j];
#pragma unroll
    for (int ni = 0; ni < 4; ++ni)
#pragma unroll
        for (int j = 0; j < 4; ++j)
            yb[(size_t)(q0 + q4 * 4 + j) * DM + h * HD + ni * 16 + r] = f2b(o[ni][j] * l[j]);
}

// ---- LDS-tiled MFMA GEMM, double-buffered: C[z] = act(scale*A[z]*B[z]^T + add) ----
template<int BM, int BN>
__global__ __launch_bounds__(256, 2)
void gemm_t(const unsigned short* __restrict__ A, int lda, long long sA,
            const unsigned short* __restrict__ B, int ldb, long long sB,
            float* Cf, unsigned short* Cb, int ldc, long long sC,
            const float* __restrict__ addsrc, int ldadd,
            int K, float scale, int act) {
    constexpr int BK = 32;
    constexpr int MI = BM / 32, NI = BN / 32;
    constexpr int CAW = BM / 64, CBW = BN / 64;
    __shared__ unsigned short As[2][BM * BK];
    __shared__ unsigned short Bs[2][BN * BK];

    int t = threadIdx.x;
    int wave = t >> 6, lane = t & 63;
    int m0 = blockIdx.y * BM, n0 = blockIdx.x * BN;
    int z = blockIdx.z;
    const unsigned short* Ab = A + (size_t)z * sA;
    const unsigned short* Bb = B + (size_t)z * sB;

    int r = lane & 15, q4 = lane >> 4;
    int sr = lane >> 2, sseg = lane & 3;
    int wmo = (wave >> 1) * (BM / 2);
    int wno = (wave & 1) * (BN / 2);

    floatx4 acc[MI][NI] = {};

    // prologue stage (k0 = 0)
#pragma unroll
    for (int j = 0; j < CAW; ++j) {
        int c = wave * CAW + j;
        const unsigned short* g = Ab + (size_t)(m0 + c * 16 + sr) * lda + sseg * 8;
        __builtin_amdgcn_global_load_lds((GU32*)g, (LU32*)(&As[0][c * 512]), 16, 0, 0);
    }
#pragma unroll
    for (int j = 0; j < CBW; ++j) {
        int c = wave * CBW + j;
        const unsigned short* g = Bb + (size_t)(n0 + c * 16 + sr) * ldb + sseg * 8;
        __builtin_amdgcn_global_load_lds((GU32*)g, (LU32*)(&Bs[0][c * 512]), 16, 0, 0);
    }
    __syncthreads();

    int cur = 0;
    for (int k0 = 0; k0 < K; k0 += BK) {
        int kn = k0 + BK;
        if (kn < K) {
#pragma unroll
            for (int j = 0; j < CAW; ++j) {
                int c = wave * CAW + j;
                const unsigned short* g = Ab + (size_t)(m0 + c * 16 + sr) * lda + kn + sseg * 8;
                __builtin_amdgcn_global_load_lds((GU32*)g, (LU32*)(&As[cur ^ 1][c * 512]), 16, 0, 0);
            }
#pragma unroll
            for (int j = 0; j < CBW; ++j) {
                int c = wave * CBW + j;
                const unsigned short* g = Bb + (size_t)(n0 + c * 16 + sr) * ldb + kn + sseg * 8;
                __builtin_amdgcn_global_load_lds((GU32*)g, (LU32*)(&Bs[cur ^ 1][c * 512]), 16, 0, 0);
            }
        }
        short8 af[MI], bfr[NI];
#pragma unroll
        for (int mi = 0; mi < MI; ++mi)
            af[mi] = *(const short8*)(&As[cur][(wmo + mi * 16 + r) * BK + q4 * 8]);
#pragma unroll
        for (int ni = 0; ni < NI; ++ni)
            bfr[ni] = *(const short8*)(&Bs[cur][(wno + ni * 16 + r) * BK + q4 * 8]);
#pragma unroll
        for (int mi = 0; mi < MI; ++mi)
#pragma unroll
            for (int ni = 0; ni < NI; ++ni)
                acc[mi][ni] = __builtin_amdgcn_mfma_f32_16x16x32_bf16(af[mi], bfr[ni], acc[mi][ni], 0, 0, 0);
        __syncthreads();
        cur ^= 1;
    }

    size_t cz = (size_t)z * sC;
#pragma unroll
    for (int mi = 0; mi < MI; ++mi) {
#pragma unroll
        for (int ni = 0; ni < NI; ++ni) {
            int col = n0 + wno + ni * 16 + r;
#pragma unroll
            for (int j = 0; j < 4; ++j) {
                int row = m0 + wmo + mi * 16 + q4 * 4 + j;
                float v = acc[mi][ni][j] * scale;
                if (addsrc) v += addsrc[(size_t)row * ldadd + col];
                if (act == 1) { v = fmaxf(v, 0.f); v = v * v; }
                if (Cf) Cf[cz + (size_t)row * ldc + col] = v;
                if (Cb) Cb[cz + (size_t)row * ldc + col] = f2b(v);
            }
        }
    }
}

// ---- Wo split-K reduce + residual + FFN rms: x = xl + p0 + p1; xhb = bf16(rms(x)) ----
__global__ void wo_rms(const float* __restrict__ xl, const float* __restrict__ pp,
                       float* __restrict__ x, unsigned short* __restrict__ xhb) {
    int row = blockIdx.x, t = threadIdx.x;
    const long n = (long)SQ * DM;
    size_t base = (size_t)row * DM;
    float a[4]; float ss = 0.f;
#pragma unroll
    for (int j = 0; j < 4; ++j) {
        size_t idx = base + t + j * 256;
        float v = xl[idx] + pp[idx] + pp[idx + n];
        x[idx] = v;
        a[j] = v; ss += v * v;
    }
    ss = bsum(ss);
    float inv = rsqrtf(ss / (float)DM + EPS);
#pragma unroll
    for (int j = 0; j < 4; ++j)
        xhb[base + t + j * 256] = f2b(a[j] * inv);
}

// ---- proj split-K reduce + next layer's xl/rms (or final rms to out) ----
__global__ void proj_reduce_xlrms(const float* __restrict__ x, const float* __restrict__ pp,
                                  const float* __restrict__ x0, const float* __restrict__ lam2,
                                  float* __restrict__ xl, unsigned short* __restrict__ xnb,
                                  float* __restrict__ out, int last) {
    int row = blockIdx.x, t = threadIdx.x;
    const long n = (long)SQ * DM;
    size_t base = (size_t)row * DM;
    float l0 = 0.f, l1 = 0.f;
    if (!last) { l0 = lam2[0]; l1 = lam2[1]; }
    float a[4]; float ss = 0.f;
#pragma unroll
    for (int j = 0; j < 4; ++j) {
        size_t idx = base + t + j * 256;
        float v = x[idx] + pp[idx] + pp[idx + n] + pp[idx + 2 * n] + pp[idx + 3 * n];
        if (!last) { v = l0 * v + l1 * x0[idx]; xl[idx] = v; }
        a[j] = v; ss += v * v;
    }
    ss = bsum(ss);
    float inv = rsqrtf(ss / (float)DM + EPS);
#pragma unroll
    for (int j = 0; j < 4; ++j) {
        size_t idx = base + t + j * 256;
        if (last) out[idx] = a[j] * inv;
        else xnb[idx] = f2b(a[j] * inv);
    }
}

extern "C" void kernel_launch(void* const* d_in, const int* in_sizes, int n_in,
                              void* d_out, int out_size, void* d_ws, size_t ws_size,
                              hipStream_t stream) {
    const float* x_in    = (const float*)d_in[0];
    const float* Wq      = (const float*)d_in[1];
    const float* Wk      = (const float*)d_in[2];
    const float* Wv      = (const float*)d_in[3];
    const float* Wo      = (const float*)d_in[4];
    const float* lamb    = (const float*)d_in[5];
    const float* lambdas = (const float*)d_in[6];
    const float* Wfc     = (const float*)d_in[7];
    const float* Wp      = (const float*)d_in[8];
    const int*   levels  = (const int*)d_in[9];
    const int*   sidx    = (const int*)d_in[10];
    float* out = (float*)d_out;

    char* ws = (char*)d_ws;
    size_t off = 0;
    auto alloc = [&](size_t b) { void* p = ws + off; off = (off + b + 255) & ~(size_t)255; return p; };

    // wq/wk/wv must remain consecutive (z-stride batching in gemm_qkv)
    unsigned short* wq_b  = (unsigned short*)alloc((size_t)NL * DM * DM * 2);
    unsigned short* wk_b  = (unsigned short*)alloc((size_t)NL * DM * DM * 2);
    unsigned short* wv_b  = (unsigned short*)alloc((size_t)NL * DM * DM * 2);
    unsigned short* wo_b  = (unsigned short*)alloc((size_t)NL * DM * DM * 2);
    unsigned short* wfc_b = (unsigned short*)alloc((size_t)NL * DFF * DM * 2);
    unsigned short* wp_b  = (unsigned short*)alloc((size_t)NL * DM * DFF * 2);
    int* cpad             = (int*)alloc((SQ + 1) * 4);
    unsigned long long* mb = (unsigned long long*)alloc((size_t)SQ * 16 * 8);
    float2* rope          = (float2*)alloc((size_t)SQ * 32 * 8);
    float* x    = (float*)alloc((size_t)SQ * DM * 4);
    float* x0   = (float*)alloc((size_t)SQ * DM * 4);
    float* xl   = (float*)alloc((size_t)SQ * DM * 4);
    float* v1   = (float*)alloc((size_t)SQ * DM * 4);
    float* pp   = (float*)alloc((size_t)4 * SQ * DM * 4);   // split-K partials (Wo uses 2, proj 4)
    unsigned short* xn_b = (unsigned short*)alloc((size_t)SQ * DM * 2);
    unsigned short* qb   = (unsigned short*)alloc((size_t)SQ * DM * 2);
    unsigned short* kb   = (unsigned short*)alloc((size_t)SQ * DM * 2);
    unsigned short* vt   = (unsigned short*)alloc((size_t)SQ * DM * 2);
    unsigned short* y_b  = (unsigned short*)alloc((size_t)SQ * DM * 2);
    unsigned short* xh_b = (unsigned short*)alloc((size_t)SQ * DM * 2);
    unsigned short* h_b  = (unsigned short*)alloc((size_t)SQ * DFF * 2);

    if (off > ws_size) return;

    const long long WSTRIDE = (long long)NL * DM * DM;
    const long long XSTRIDE = (long long)SQ * DM;

    convert_all<<<18432, 256, 0, stream>>>(Wq, Wk, Wv, Wo, Wfc, Wp,
                                           wq_b, wk_b, wv_b, wo_b, wfc_b, wp_b);

    scan_levels<<<1, 1024, 0, stream>>>(levels, cpad);
    build_mask_bits<<<4096, 256, 0, stream>>>(levels, sidx, cpad, mb);
    build_rope<<<128, 256, 0, stream>>>(rope);

    rms0<<<SQ, 256, 0, stream>>>(x_in, lambdas, x0, xl, xn_b);

    for (int i = 0; i < NL; ++i) {
        // fused QKV, 64x128 tiles, z selects Wq/Wk/Wv; epilogues: q/k rms+rope, v blend+transpose
        gemm_qkv<<<dim3(8, 16, 3), 256, 0, stream>>>(
            xn_b, wq_b + (size_t)i * DM * DM, WSTRIDE, qb, kb, v1, vt, rope,
            lamb + i, (i == 0) ? 1 : 0);

        flash_attn<<<1024, 64, 0, stream>>>(qb, kb, vt, mb, y_b);

        // y @ Wo^T, split-K=2 (64x64 tiles, 512 blocks) -> partials
        gemm_t<64, 64><<<dim3(16, 16, 2), 256, 0, stream>>>(
            y_b, DM, 512, wo_b + (size_t)i * DM * DM, DM, 512,
            pp, nullptr, DM, XSTRIDE, nullptr, 0, 512, 1.f, 0);
        // x = xl + p0 + p1; xh_b = rms(x)
        wo_rms<<<SQ, 256, 0, stream>>>(xl, pp, x, xh_b);

        // FFN fc: 128x64 tiles, 512 blocks, relu^2 epilogue
        gemm_t<128, 64><<<dim3(64, 8, 1), 256, 0, stream>>>(
            xh_b, DM, 0, wfc_b + (size_t)i * DFF * DM, DM, 0,
            nullptr, h_b, DFF, 0, nullptr, 0, DM, 1.f, 1);
        // proj: split-K=4, 128x64 tiles, 512 blocks
        gemm_t<128, 64><<<dim3(16, 8, 4), 256, 0, stream>>>(
            h_b, DFF, 1024, wp_b + (size_t)i * DM * DFF, DFF, 1024,
            pp, nullptr, DM, XSTRIDE, nullptr, 0, 1024, 1.f, 0);
        // x += 4 partials; next layer xl/xn (or final rms -> out)
        proj_reduce_xlrms<<<SQ, 256, 0, stream>>>(
            x, pp, x0, (i < NL - 1) ? (lambdas + 2 * (i + 1)) : nullptr,
            xl, xn_b, out, (i == NL - 1) ? 1 : 0);
    }
}

// Round 3
// 1006.614 us; speedup vs baseline: 1.0538x; 1.0538x over previous
//
#include <hip/hip_runtime.h>

#define SQ 1024
#define DM 1024
#define NH 16
#define HD 64
#define NL 6
#define DFF 4096
#define EPS 1.1920929e-07f

typedef __attribute__((ext_vector_type(8))) short short8;
typedef __attribute__((ext_vector_type(4))) float floatx4;
typedef __attribute__((address_space(1))) const unsigned int GU32;
typedef __attribute__((address_space(3))) unsigned int LU32;

__device__ __forceinline__ unsigned short f2b(float f) {
    union { float f; unsigned int u; } x; x.f = f;
    unsigned int r = x.u + 0x7fffu + ((x.u >> 16) & 1u);
    return (unsigned short)(r >> 16);
}

__device__ __forceinline__ float wsum(float v) {
#pragma unroll
    for (int m = 32; m >= 1; m >>= 1) v += __shfl_xor(v, m, 64);
    return v;
}
__device__ __forceinline__ float bsum(float v) {
    __shared__ float sh[4];
    v = wsum(v);
    __syncthreads();
    if ((threadIdx.x & 63) == 0) sh[threadIdx.x >> 6] = v;
    __syncthreads();
    return sh[0] + sh[1] + sh[2] + sh[3];
}

// ---- f32 -> bf16 conversion: 32B/lane loads, 16B/lane stores ----
__global__ void convert_all(const float* __restrict__ s0, const float* __restrict__ s1,
                            const float* __restrict__ s2, const float* __restrict__ s3,
                            const float* __restrict__ s4, const float* __restrict__ s5,
                            unsigned short* __restrict__ d0, unsigned short* __restrict__ d1,
                            unsigned short* __restrict__ d2, unsigned short* __restrict__ d3,
                            unsigned short* __restrict__ d4, unsigned short* __restrict__ d5) {
    int bid = blockIdx.x;
    const float* src; unsigned short* dst; long base;   // base in float8 units
    if (bid < 1536)        { src = s0; dst = d0; base = (long)bid * 512; }
    else if (bid < 3072)   { src = s1; dst = d1; base = (long)(bid - 1536) * 512; }
    else if (bid < 4608)   { src = s2; dst = d2; base = (long)(bid - 3072) * 512; }
    else if (bid < 6144)   { src = s3; dst = d3; base = (long)(bid - 4608) * 512; }
    else if (bid < 12288)  { src = s4; dst = d4; base = (long)(bid - 6144) * 512; }
    else                   { src = s5; dst = d5; base = (long)(bid - 12288) * 512; }
    long i0 = base + threadIdx.x;
#pragma unroll
    for (int u = 0; u < 2; ++u) {
        long i = i0 + u * 256;
        float4 a = ((const float4*)src)[2 * i];
        float4 b = ((const float4*)src)[2 * i + 1];
        short8 o;
        o[0] = (short)f2b(a.x); o[1] = (short)f2b(a.y);
        o[2] = (short)f2b(a.z); o[3] = (short)f2b(a.w);
        o[4] = (short)f2b(b.x); o[5] = (short)f2b(b.y);
        o[6] = (short)f2b(b.z); o[7] = (short)f2b(b.w);
        *(short8*)(dst + i * 8) = o;
    }
}

// ---- rope cos/sin table ----
__global__ void build_rope(float2* __restrict__ tab) {
    int i = blockIdx.x * 256 + threadIdx.x;     // 32768 entries
    int s = i >> 5, d = i & 31;
    float invf = expf(-((float)(2 * d) / (float)HD) * 9.210340371976184f);
    float fr = (float)s * invf;
    tab[i] = make_float2(cosf(fr), sinf(fr));
}

// ---- markov mask prep ----
__global__ void scan_levels(const int* __restrict__ levels, int* __restrict__ cpad) {
    __shared__ int sh[SQ];
    int t = threadIdx.x;
    sh[t] = (levels[t] == 0) ? 1 : 0;
    __syncthreads();
    for (int off = 1; off < SQ; off <<= 1) {
        int v = (t >= off) ? sh[t - off] : 0;
        __syncthreads();
        sh[t] += v;
        __syncthreads();
    }
    cpad[t + 1] = sh[t];
    if (t == 0) cpad[0] = 0;
}

__global__ void build_mask_bits(const int* __restrict__ levels, const int* __restrict__ sidx,
                                const int* __restrict__ cpad, unsigned long long* __restrict__ mb) {
    int i = blockIdx.x * 256 + threadIdx.x;
    int q = i >> 10, k = i & 1023;
    bool causal = q >= k;
    bool same = sidx[q] == sidx[k];
    int cnt = cpad[q] - cpad[k + 1];
    bool markov = (levels[k] == 0) && (cnt > 0);
    bool pred = causal && same && !markov;
    unsigned long long bal = __ballot(pred);
    if ((threadIdx.x & 63) == 0) mb[(size_t)q * 16 + (k >> 6)] = bal;
}

// ---- initial: r = rms(x_in); x0 = r; xl = (l0+l1)*r; xnb = bf16(rms(xl)) ----
__global__ void rms0(const float* __restrict__ xin, const float* __restrict__ lam2,
                     float* __restrict__ x0, float* __restrict__ xl,
                     unsigned short* __restrict__ xnb) {
    int row = blockIdx.x, t = threadIdx.x;
    float l0 = lam2[0], l1 = lam2[1];
    const float* rp = xin + (size_t)row * DM;
    float v[4]; float ss = 0.f;
#pragma unroll
    for (int j = 0; j < 4; ++j) { v[j] = rp[t + j * 256]; ss += v[j] * v[j]; }
    ss = bsum(ss);
    float inv = rsqrtf(ss / (float)DM + EPS);
    float coef = l0 + l1;
    float w[4]; float ss2 = 0.f;
#pragma unroll
    for (int j = 0; j < 4; ++j) {
        float r = v[j] * inv;
        x0[(size_t)row * DM + t + j * 256] = r;
        w[j] = coef * r;
        ss2 += w[j] * w[j];
    }
    ss2 = bsum(ss2);
    float inv2 = rsqrtf(ss2 / (float)DM + EPS);
#pragma unroll
    for (int j = 0; j < 4; ++j) {
        size_t idx = (size_t)row * DM + t + j * 256;
        xl[idx] = w[j];
        xnb[idx] = f2b(w[j] * inv2);
    }
}

// ---- fused QKV GEMM 64x128, BK=64, single-buffer LDS (m97 structure) ----
// z=0/1 -> head-rms + rope -> qb/kb (bf16); z=2 -> v blend + transpose -> vt (bf16)
__global__ __launch_bounds__(256, 2)
void gemm_qkv(const unsigned short* __restrict__ A,      // xn_b [S][D]
              const unsigned short* __restrict__ B0,     // wq_b + i*D*D (wk,wv at z*sB)
              long long sB,
              unsigned short* __restrict__ qb, unsigned short* __restrict__ kb,
              float* __restrict__ v1, unsigned short* __restrict__ vt,
              const float2* __restrict__ rope,
              const float* __restrict__ lambp, int first) {
    constexpr int BM = 64, BN = 128, BK = 64;
    __shared__ unsigned short As[BM * BK];       // 8 KB
    __shared__ unsigned short Bs[BN * BK];       // 16 KB
    __shared__ unsigned short vtile[128 * 72];   // 18 KB (pad 72 to break conflicts)
    int t = threadIdx.x, wave = t >> 6, lane = t & 63;
    int m0 = blockIdx.y * BM, n0 = blockIdx.x * BN;
    int z = blockIdx.z;
    const unsigned short* Bb = B0 + (size_t)z * sB;
    int r = lane & 15, q4 = lane >> 4;
    int sr8 = lane >> 3, sseg8 = lane & 7;       // 8-row chunk staging (1 KB per gload_lds)
    int wmo = (wave >> 1) * 32, wno = (wave & 1) * 64;

    floatx4 acc[2][4] = {};

    for (int k0 = 0; k0 < DM; k0 += BK) {
        // A: 8 chunks of 8 rows, 2 per wave
#pragma unroll
        for (int j = 0; j < 2; ++j) {
            int c = wave * 2 + j;
            const unsigned short* g = A + (size_t)(m0 + c * 8 + sr8) * DM + k0 + sseg8 * 8;
            __builtin_amdgcn_global_load_lds((GU32*)g, (LU32*)(As + c * 512), 16, 0, 0);
        }
        // B: 16 chunks, 4 per wave
#pragma unroll
        for (int j = 0; j < 4; ++j) {
            int c = wave * 4 + j;
            const unsigned short* g = Bb + (size_t)(n0 + c * 8 + sr8) * DM + k0 + sseg8 * 8;
            __builtin_amdgcn_global_load_lds((GU32*)g, (LU32*)(Bs + c * 512), 16, 0, 0);
        }
        __syncthreads();
#pragma unroll
        for (int kk = 0; kk < 2; ++kk) {
            short8 af[2], bfr[4];
#pragma unroll
            for (int mi = 0; mi < 2; ++mi)
                af[mi] = *(const short8*)(As + (wmo + mi * 16 + r) * BK + kk * 32 + q4 * 8);
#pragma unroll
            for (int ni = 0; ni < 4; ++ni)
                bfr[ni] = *(const short8*)(Bs + (wno + ni * 16 + r) * BK + kk * 32 + q4 * 8);
#pragma unroll
            for (int mi = 0; mi < 2; ++mi)
#pragma unroll
                for (int ni = 0; ni < 4; ++ni)
                    acc[mi][ni] = __builtin_amdgcn_mfma_f32_16x16x32_bf16(af[mi], bfr[ni], acc[mi][ni], 0, 0, 0);
        }
        __syncthreads();
    }

    if (z == 2) {
        // v blend (with v1) -> bf16 -> LDS tile -> transposed write to vt
        float l = lambp[0];
#pragma unroll
        for (int mi = 0; mi < 2; ++mi)
#pragma unroll
            for (int ni = 0; ni < 4; ++ni)
#pragma unroll
                for (int j = 0; j < 4; ++j) {
                    int row = m0 + wmo + mi * 16 + q4 * 4 + j;
                    int col = n0 + wno + ni * 16 + r;
                    float val = acc[mi][ni][j];
                    size_t gi = (size_t)row * DM + col;
                    float v1v;
                    if (first) { v1[gi] = val; v1v = val; } else v1v = v1[gi];
                    vtile[(col - n0) * 72 + (row - m0)] = f2b((1.f - l) * val + l * v1v);
                }
        __syncthreads();
#pragma unroll
        for (int jj = 0; jj < 4; ++jj) {
            int idx = jj * 256 + t;      // 0..1023
            int cr = idx >> 3;           // 0..127
            int seg = idx & 7;
            short8 o = *(const short8*)(&vtile[cr * 72 + seg * 8]);
            *(short8*)(vt + (size_t)(n0 + cr) * SQ + m0 + seg * 8) = o;
        }
        return;
    }

    unsigned short* dst = z ? kb : qb;
    // wave owns exactly one 64-col head: cols n0+wno + ni*16 + r
#pragma unroll
    for (int mi = 0; mi < 2; ++mi) {
#pragma unroll
        for (int j = 0; j < 4; ++j) {
            int row = m0 + wmo + mi * 16 + q4 * 4 + j;
            float v0 = acc[mi][0][j], v1x = acc[mi][1][j], v2 = acc[mi][2][j], v3 = acc[mi][3][j];
            float ss = v0 * v0 + v1x * v1x + v2 * v2 + v3 * v3;
#pragma unroll
            for (int d = 1; d < 16; d <<= 1) ss += __shfl_xor(ss, d, 64);
            float inv = rsqrtf(ss * (1.f / 64.f) + EPS);
            v0 *= inv; v1x *= inv; v2 *= inv; v3 *= inv;
            float2 t0 = rope[row * 32 + r];
            float2 t1 = rope[row * 32 + 16 + r];
            size_t rb = (size_t)row * DM + n0 + wno + r;
            dst[rb]      = f2b(v0 * t0.x + v2 * t0.y);
            dst[rb + 16] = f2b(v1x * t1.x + v3 * t1.y);
            dst[rb + 32] = f2b(v2 * t0.x - v0 * t0.y);
            dst[rb + 48] = f2b(v3 * t1.x - v1x * t1.y);
        }
    }
}

// ---- fused flash attention: one wave per (16-row q-tile, head) ----
__global__ __launch_bounds__(64)
void flash_attn(const unsigned short* __restrict__ qb, const unsigned short* __restrict__ kb,
                const unsigned short* __restrict__ vt, const unsigned long long* __restrict__ mb,
                unsigned short* __restrict__ yb) {
    __shared__ unsigned short Ps[16 * 64];
    int lane = threadIdx.x;
    int qt = blockIdx.x & 63, h = blockIdx.x >> 6;
    int q0 = qt * 16;
    int r = lane & 15, q4 = lane >> 4;
    const unsigned short* qp = qb + (size_t)(q0 + r) * DM + h * HD + q4 * 8;
    short8 aq0 = *(const short8*)qp;
    short8 aq1 = *(const short8*)(qp + 32);
    floatx4 o[4] = {};
    float m[4] = {-1e30f, -1e30f, -1e30f, -1e30f};
    float l[4] = {0.f, 0.f, 0.f, 0.f};
    int nk = (qt >> 2) + 1;
    for (int kt = 0; kt < nk; ++kt) {
        int k0 = kt * 64;
        unsigned long long mw[4];
#pragma unroll
        for (int j = 0; j < 4; ++j) mw[j] = mb[(size_t)(q0 + q4 * 4 + j) * 16 + kt];
        unsigned long long any = mw[0] | mw[1] | mw[2] | mw[3];
        if (__ballot(any != 0ull) == 0ull) continue;
        short8 bk[4][2], bv[4][2];
#pragma unroll
        for (int ni = 0; ni < 4; ++ni) {
            const unsigned short* kp = kb + (size_t)(k0 + ni * 16 + r) * DM + h * HD + q4 * 8;
            bk[ni][0] = *(const short8*)kp;
            bk[ni][1] = *(const short8*)(kp + 32);
            const unsigned short* vp = vt + (size_t)(h * HD + ni * 16 + r) * SQ + k0 + q4 * 8;
            bv[ni][0] = *(const short8*)vp;
            bv[ni][1] = *(const short8*)(vp + 32);
        }
        float sm[4][4];
#pragma unroll
        for (int ni = 0; ni < 4; ++ni) {
            floatx4 z = {};
            z = __builtin_amdgcn_mfma_f32_16x16x32_bf16(aq0, bk[ni][0], z, 0, 0, 0);
            z = __builtin_amdgcn_mfma_f32_16x16x32_bf16(aq1, bk[ni][1], z, 0, 0, 0);
#pragma unroll
            for (int j = 0; j < 4; ++j) {
                float sv = z[j] * 0.125f;
                bool bit = (mw[j] >> (ni * 16 + r)) & 1ull;
                sm[ni][j] = bit ? sv : -__builtin_inff();
            }
        }
        float alpha[4];
#pragma unroll
        for (int j = 0; j < 4; ++j) {
            float v = fmaxf(fmaxf(sm[0][j], sm[1][j]), fmaxf(sm[2][j], sm[3][j]));
#pragma unroll
            for (int d = 1; d < 16; d <<= 1) v = fmaxf(v, __shfl_xor(v, d, 64));
            float mn = fmaxf(m[j], v);
            alpha[j] = __expf(m[j] - mn);
            m[j] = mn;
        }
        float p[4][4];
        float rs[4] = {0.f, 0.f, 0.f, 0.f};
#pragma unroll
        for (int ni = 0; ni < 4; ++ni)
#pragma unroll
            for (int j = 0; j < 4; ++j) {
                p[ni][j] = __expf(sm[ni][j] - m[j]);
                rs[j] += p[ni][j];
            }
#pragma unroll
        for (int j = 0; j < 4; ++j) {
            float v = rs[j];
#pragma unroll
            for (int d = 1; d < 16; d <<= 1) v += __shfl_xor(v, d, 64);
            l[j] = l[j] * alpha[j] + v;
        }
#pragma unroll
        for (int ni = 0; ni < 4; ++ni)
#pragma unroll
            for (int j = 0; j < 4; ++j) {
                o[ni][j] *= alpha[j];
                Ps[(q4 * 4 + j) * 64 + ni * 16 + r] = f2b(p[ni][j]);
            }
        short8 ap0 = *(const short8*)(Ps + r * 64 + q4 * 8);
        short8 ap1 = *(const short8*)(Ps + r * 64 + 32 + q4 * 8);
#pragma unroll
        for (int ni = 0; ni < 4; ++ni) {
            o[ni] = __builtin_amdgcn_mfma_f32_16x16x32_bf16(ap0, bv[ni][0], o[ni], 0, 0, 0);
            o[ni] = __builtin_amdgcn_mfma_f32_16x16x32_bf16(ap1, bv[ni][1], o[ni], 0, 0, 0);
        }
    }
#pragma unroll
    for (int j = 0; j < 4; ++j) l[j] = 1.f / l[j];
#pragma unroll
    for (int ni = 0; ni < 4; ++ni)
#pragma unroll
        for (int j = 0; j < 4; ++j)
            yb[(size_t)(q0 + q4 * 4 + j) * DM + h * HD + ni * 16 + r] = f2b(o[ni][j] * l[j]);
}

// ---- LDS-tiled MFMA GEMM, BK=64, single-buffer (m97 structure) ----
// C[z] = act(scale*A[z]*B[z]^T + add)
template<int BM, int BN>
__global__ __launch_bounds__(256, 2)
void gemm_t(const unsigned short* __restrict__ A, int lda, long long sA,
            const unsigned short* __restrict__ B, int ldb, long long sB,
            float* Cf, unsigned short* Cb, int ldc, long long sC,
            const float* __restrict__ addsrc, int ldadd,
            int K, float scale, int act) {
    constexpr int BK = 64;
    constexpr int MI = BM / 32, NI = BN / 32;
    constexpr int CAW = BM / 32, CBW = BN / 32;   // 8-row chunks per wave
    __shared__ unsigned short As[BM * BK];
    __shared__ unsigned short Bs[BN * BK];

    int t = threadIdx.x;
    int wave = t >> 6, lane = t & 63;
    int m0 = blockIdx.y * BM, n0 = blockIdx.x * BN;
    int z = blockIdx.z;
    const unsigned short* Ab = A + (size_t)z * sA;
    const unsigned short* Bb = B + (size_t)z * sB;

    int r = lane & 15, q4 = lane >> 4;
    int sr8 = lane >> 3, sseg8 = lane & 7;
    int wmo = (wave >> 1) * (BM / 2);
    int wno = (wave & 1) * (BN / 2);

    floatx4 acc[MI][NI] = {};

    for (int k0 = 0; k0 < K; k0 += BK) {
#pragma unroll
        for (int j = 0; j < CAW; ++j) {
            int c = wave * CAW + j;
            const unsigned short* g = Ab + (size_t)(m0 + c * 8 + sr8) * lda + k0 + sseg8 * 8;
            __builtin_amdgcn_global_load_lds((GU32*)g, (LU32*)(As + c * 512), 16, 0, 0);
        }
#pragma unroll
        for (int j = 0; j < CBW; ++j) {
            int c = wave * CBW + j;
            const unsigned short* g = Bb + (size_t)(n0 + c * 8 + sr8) * ldb + k0 + sseg8 * 8;
            __builtin_amdgcn_global_load_lds((GU32*)g, (LU32*)(Bs + c * 512), 16, 0, 0);
        }
        __syncthreads();
#pragma unroll
        for (int kk = 0; kk < 2; ++kk) {
            short8 af[MI], bfr[NI];
#pragma unroll
            for (int mi = 0; mi < MI; ++mi)
                af[mi] = *(const short8*)(As + (wmo + mi * 16 + r) * BK + kk * 32 + q4 * 8);
#pragma unroll
            for (int ni = 0; ni < NI; ++ni)
                bfr[ni] = *(const short8*)(Bs + (wno + ni * 16 + r) * BK + kk * 32 + q4 * 8);
#pragma unroll
            for (int mi = 0; mi < MI; ++mi)
#pragma unroll
                for (int ni = 0; ni < NI; ++ni)
                    acc[mi][ni] = __builtin_amdgcn_mfma_f32_16x16x32_bf16(af[mi], bfr[ni], acc[mi][ni], 0, 0, 0);
        }
        __syncthreads();
    }

    size_t cz = (size_t)z * sC;
#pragma unroll
    for (int mi = 0; mi < MI; ++mi) {
#pragma unroll
        for (int ni = 0; ni < NI; ++ni) {
            int col = n0 + wno + ni * 16 + r;
#pragma unroll
            for (int j = 0; j < 4; ++j) {
                int row = m0 + wmo + mi * 16 + q4 * 4 + j;
                float v = acc[mi][ni][j] * scale;
                if (addsrc) v += addsrc[(size_t)row * ldadd + col];
                if (act == 1) { v = fmaxf(v, 0.f); v = v * v; }
                if (Cf) Cf[cz + (size_t)row * ldc + col] = v;
                if (Cb) Cb[cz + (size_t)row * ldc + col] = f2b(v);
            }
        }
    }
}

// ---- Wo split-K reduce + residual + FFN rms: x = xl + p0 + p1; xhb = bf16(rms(x)) ----
__global__ void wo_rms(const float* __restrict__ xl, const float* __restrict__ pp,
                       float* __restrict__ x, unsigned short* __restrict__ xhb) {
    int row = blockIdx.x, t = threadIdx.x;
    const long n = (long)SQ * DM;
    size_t base = (size_t)row * DM;
    float a[4]; float ss = 0.f;
#pragma unroll
    for (int j = 0; j < 4; ++j) {
        size_t idx = base + t + j * 256;
        float v = xl[idx] + pp[idx] + pp[idx + n];
        x[idx] = v;
        a[j] = v; ss += v * v;
    }
    ss = bsum(ss);
    float inv = rsqrtf(ss / (float)DM + EPS);
#pragma unroll
    for (int j = 0; j < 4; ++j)
        xhb[base + t + j * 256] = f2b(a[j] * inv);
}

// ---- proj split-K reduce + next layer's xl/rms (or final rms to out) ----
__global__ void proj_reduce_xlrms(const float* __restrict__ x, const float* __restrict__ pp,
                                  const float* __restrict__ x0, const float* __restrict__ lam2,
                                  float* __restrict__ xl, unsigned short* __restrict__ xnb,
                                  float* __restrict__ out, int last) {
    int row = blockIdx.x, t = threadIdx.x;
    const long n = (long)SQ * DM;
    size_t base = (size_t)row * DM;
    float l0 = 0.f, l1 = 0.f;
    if (!last) { l0 = lam2[0]; l1 = lam2[1]; }
    float a[4]; float ss = 0.f;
#pragma unroll
    for (int j = 0; j < 4; ++j) {
        size_t idx = base + t + j * 256;
        float v = x[idx] + pp[idx] + pp[idx + n] + pp[idx + 2 * n] + pp[idx + 3 * n];
        if (!last) { v = l0 * v + l1 * x0[idx]; xl[idx] = v; }
        a[j] = v; ss += v * v;
    }
    ss = bsum(ss);
    float inv = rsqrtf(ss / (float)DM + EPS);
#pragma unroll
    for (int j = 0; j < 4; ++j) {
        size_t idx = base + t + j * 256;
        if (last) out[idx] = a[j] * inv;
        else xnb[idx] = f2b(a[j] * inv);
    }
}

extern "C" void kernel_launch(void* const* d_in, const int* in_sizes, int n_in,
                              void* d_out, int out_size, void* d_ws, size_t ws_size,
                              hipStream_t stream) {
    const float* x_in    = (const float*)d_in[0];
    const float* Wq      = (const float*)d_in[1];
    const float* Wk      = (const float*)d_in[2];
    const float* Wv      = (const float*)d_in[3];
    const float* Wo      = (const float*)d_in[4];
    const float* lamb    = (const float*)d_in[5];
    const float* lambdas = (const float*)d_in[6];
    const float* Wfc     = (const float*)d_in[7];
    const float* Wp      = (const float*)d_in[8];
    const int*   levels  = (const int*)d_in[9];
    const int*   sidx    = (const int*)d_in[10];
    float* out = (float*)d_out;

    char* ws = (char*)d_ws;
    size_t off = 0;
    auto alloc = [&](size_t b) { void* p = ws + off; off = (off + b + 255) & ~(size_t)255; return p; };

    // wq/wk/wv must remain consecutive (z-stride batching in gemm_qkv)
    unsigned short* wq_b  = (unsigned short*)alloc((size_t)NL * DM * DM * 2);
    unsigned short* wk_b  = (unsigned short*)alloc((size_t)NL * DM * DM * 2);
    unsigned short* wv_b  = (unsigned short*)alloc((size_t)NL * DM * DM * 2);
    unsigned short* wo_b  = (unsigned short*)alloc((size_t)NL * DM * DM * 2);
    unsigned short* wfc_b = (unsigned short*)alloc((size_t)NL * DFF * DM * 2);
    unsigned short* wp_b  = (unsigned short*)alloc((size_t)NL * DM * DFF * 2);
    int* cpad             = (int*)alloc((SQ + 1) * 4);
    unsigned long long* mb = (unsigned long long*)alloc((size_t)SQ * 16 * 8);
    float2* rope          = (float2*)alloc((size_t)SQ * 32 * 8);
    float* x    = (float*)alloc((size_t)SQ * DM * 4);
    float* x0   = (float*)alloc((size_t)SQ * DM * 4);
    float* xl   = (float*)alloc((size_t)SQ * DM * 4);
    float* v1   = (float*)alloc((size_t)SQ * DM * 4);
    float* pp   = (float*)alloc((size_t)4 * SQ * DM * 4);   // split-K partials (Wo uses 2, proj 4)
    unsigned short* xn_b = (unsigned short*)alloc((size_t)SQ * DM * 2);
    unsigned short* qb   = (unsigned short*)alloc((size_t)SQ * DM * 2);
    unsigned short* kb   = (unsigned short*)alloc((size_t)SQ * DM * 2);
    unsigned short* vt   = (unsigned short*)alloc((size_t)SQ * DM * 2);
    unsigned short* y_b  = (unsigned short*)alloc((size_t)SQ * DM * 2);
    unsigned short* xh_b = (unsigned short*)alloc((size_t)SQ * DM * 2);
    unsigned short* h_b  = (unsigned short*)alloc((size_t)SQ * DFF * 2);

    if (off > ws_size) return;

    const long long WSTRIDE = (long long)NL * DM * DM;
    const long long XSTRIDE = (long long)SQ * DM;

    convert_all<<<18432, 256, 0, stream>>>(Wq, Wk, Wv, Wo, Wfc, Wp,
                                           wq_b, wk_b, wv_b, wo_b, wfc_b, wp_b);

    scan_levels<<<1, 1024, 0, stream>>>(levels, cpad);
    build_mask_bits<<<4096, 256, 0, stream>>>(levels, sidx, cpad, mb);
    build_rope<<<128, 256, 0, stream>>>(rope);

    rms0<<<SQ, 256, 0, stream>>>(x_in, lambdas, x0, xl, xn_b);

    for (int i = 0; i < NL; ++i) {
        // fused QKV, 64x128 tiles, z selects Wq/Wk/Wv; epilogues: q/k rms+rope, v blend+transpose
        gemm_qkv<<<dim3(8, 16, 3), 256, 0, stream>>>(
            xn_b, wq_b + (size_t)i * DM * DM, WSTRIDE, qb, kb, v1, vt, rope,
            lamb + i, (i == 0) ? 1 : 0);

        flash_attn<<<1024, 64, 0, stream>>>(qb, kb, vt, mb, y_b);

        // y @ Wo^T, split-K=2 (64x64 tiles, 512 blocks) -> partials
        gemm_t<64, 64><<<dim3(16, 16, 2), 256, 0, stream>>>(
            y_b, DM, 512, wo_b + (size_t)i * DM * DM, DM, 512,
            pp, nullptr, DM, XSTRIDE, nullptr, 0, 512, 1.f, 0);
        // x = xl + p0 + p1; xh_b = rms(x)
        wo_rms<<<SQ, 256, 0, stream>>>(xl, pp, x, xh_b);

        // FFN fc: 128x64 tiles, 512 blocks, relu^2 epilogue
        gemm_t<128, 64><<<dim3(64, 8, 1), 256, 0, stream>>>(
            xh_b, DM, 0, wfc_b + (size_t)i * DFF * DM, DM, 0,
            nullptr, h_b, DFF, 0, nullptr, 0, DM, 1.f, 1);
        // proj: split-K=4, 128x64 tiles, 512 blocks
        gemm_t<128, 64><<<dim3(16, 8, 4), 256, 0, stream>>>(
            h_b, DFF, 1024, wp_b + (size_t)i * DM * DFF, DFF, 1024,
            pp, nullptr, DM, XSTRIDE, nullptr, 0, 1024, 1.f, 0);
        // x += 4 partials; next layer xl/xn (or final rms -> out)
        proj_reduce_xlrms<<<SQ, 256, 0, stream>>>(
            x, pp, x0, (i < NL - 1) ? (lambdas + 2 * (i + 1)) : nullptr,
            xl, xn_b, out, (i == NL - 1) ? 1 : 0);
    }
}